// Round 1
// baseline (1716.319 us; speedup 1.0000x reference)
//
#include <hip/hip_runtime.h>

#define NN 100000
#define NE 3200000
#define NF 128
#define NH 64
#define NG 512
#define NC 3
#define BN_EPS 1e-5f

// ---------------- degree / dinv ----------------
__global__ __launch_bounds__(256) void k_init_deg(float* __restrict__ deg) {
    int i = blockIdx.x * 256 + threadIdx.x;
    if (i < NN) deg[i] = 1.0f;  // self-loop
}

__global__ __launch_bounds__(256) void k_degree(const int* __restrict__ dst, float* __restrict__ deg) {
    int stride = gridDim.x * 256;
    for (int e = blockIdx.x * 256 + threadIdx.x; e < NE; e += stride)
        atomicAdd(&deg[dst[e]], 1.0f);
}

__global__ __launch_bounds__(256) void k_rsqrt(float* __restrict__ deg) {
    int i = blockIdx.x * 256 + threadIdx.x;
    if (i < NN) deg[i] = rsqrtf(deg[i]);  // deg >= 1 always
}

// ---------------- GEMM: out[M][64] = X[M][K] @ W[K][64] ----------------
// 128 rows/block, 256 threads, each thread: 4 rows x 8 cols.
// LDS: xs 128x68 (pad 4 -> bank stride 4, conflict-free), ws 64x64 (2-way, free).
template <int K>
__global__ __launch_bounds__(256) void k_gemm(const float* __restrict__ X,
                                              const float* __restrict__ W,
                                              float* __restrict__ out, int M) {
    __shared__ float xs[128 * 68];
    __shared__ float ws[64 * 64];
    const int t = threadIdx.x;
    const int row0 = blockIdx.x * 128;
    const int rg = t >> 3;         // 0..31
    const int f0 = (t & 7) * 8;    // 0..56

    float acc[4][8];
#pragma unroll
    for (int j = 0; j < 4; j++)
#pragma unroll
        for (int c = 0; c < 8; c++) acc[j][c] = 0.0f;

    for (int kc = 0; kc < K; kc += 64) {
        __syncthreads();
        // stage W chunk (4096 floats, contiguous)
        const float4* Wg = (const float4*)(W + (size_t)kc * 64);
        float4* ws4 = (float4*)ws;
#pragma unroll
        for (int i = 0; i < 4; i++) ws4[t + i * 256] = Wg[t + i * 256];
        // stage X chunk: 128 rows x 64 cols
#pragma unroll
        for (int p = 0; p < 8; p++) {
            int rr = p * 16 + (t >> 4);
            int c4 = (t & 15) * 4;
            int row = row0 + rr;
            float4 v = make_float4(0.f, 0.f, 0.f, 0.f);
            if (row < M) v = *(const float4*)(X + (size_t)row * K + kc + c4);
            *(float4*)(&xs[rr * 68 + c4]) = v;
        }
        __syncthreads();

        for (int kk = 0; kk < 64; kk += 4) {
            float4 xv[4];
#pragma unroll
            for (int j = 0; j < 4; j++)
                xv[j] = *(const float4*)(&xs[(rg + 32 * j) * 68 + kk]);
#pragma unroll
            for (int kki = 0; kki < 4; kki++) {
                float4 w0 = *(const float4*)(&ws[(kk + kki) * 64 + f0]);
                float4 w1 = *(const float4*)(&ws[(kk + kki) * 64 + f0 + 4]);
#pragma unroll
                for (int j = 0; j < 4; j++) {
                    float a = (&xv[j].x)[kki];
                    acc[j][0] = fmaf(a, w0.x, acc[j][0]);
                    acc[j][1] = fmaf(a, w0.y, acc[j][1]);
                    acc[j][2] = fmaf(a, w0.z, acc[j][2]);
                    acc[j][3] = fmaf(a, w0.w, acc[j][3]);
                    acc[j][4] = fmaf(a, w1.x, acc[j][4]);
                    acc[j][5] = fmaf(a, w1.y, acc[j][5]);
                    acc[j][6] = fmaf(a, w1.z, acc[j][6]);
                    acc[j][7] = fmaf(a, w1.w, acc[j][7]);
                }
            }
        }
    }

#pragma unroll
    for (int j = 0; j < 4; j++) {
        int row = row0 + rg + 32 * j;
        if (row < M) {
            float4* o = (float4*)(out + (size_t)row * 64 + f0);
            o[0] = make_float4(acc[j][0], acc[j][1], acc[j][2], acc[j][3]);
            o[1] = make_float4(acc[j][4], acc[j][5], acc[j][6], acc[j][7]);
        }
    }
}

// ---------------- edge aggregation: agg[d] += h[s] * dinv[s]*dinv[d] ----------------
// one wave per edge (lane = feature); edge/dinv reads forced scalar via readfirstlane.
#define AGG_BLOCKS 2048
#define AGG_WAVES (AGG_BLOCKS * 4)
#define AGG_CHUNK ((NE + AGG_WAVES - 1) / AGG_WAVES)

__global__ __launch_bounds__(256) void k_aggregate(const float* __restrict__ h,
                                                   const int* __restrict__ src,
                                                   const int* __restrict__ dst,
                                                   const float* __restrict__ dinv,
                                                   float* __restrict__ agg) {
    const int lane = threadIdx.x & 63;
    int wid = (blockIdx.x * 256 + threadIdx.x) >> 6;
    int e0 = wid * AGG_CHUNK;
    int e1 = e0 + AGG_CHUNK;
    if (e1 > NE) e1 = NE;
    for (int e = e0; e < e1; e++) {
        int eu = __builtin_amdgcn_readfirstlane(e);
        int s = src[eu];
        int d = dst[eu];
        float norm = dinv[s] * dinv[d];
        float v = h[(size_t)s * 64 + lane] * norm;
        atomicAdd(&agg[(size_t)d * 64 + lane], v);
    }
}

// ---------------- self-term + bias + BN + ReLU (in place on agg) ----------------
__global__ __launch_bounds__(256) void k_post(float* __restrict__ agg, const float* __restrict__ h,
                                              const float* __restrict__ dinv,
                                              const float* __restrict__ bias,
                                              const float* __restrict__ gam,
                                              const float* __restrict__ bet,
                                              const float* __restrict__ rm,
                                              const float* __restrict__ rv) {
    int i = blockIdx.x * 256 + threadIdx.x;
    if (i >= NN * 64) return;
    int n = i >> 6, f = i & 63;
    float di = dinv[n];
    float val = agg[i] + h[i] * di * di + bias[f];
    float y = (val - rm[f]) * rsqrtf(rv[f] + BN_EPS) * gam[f] + bet[f];
    agg[i] = fmaxf(y, 0.0f);
}

// ---------------- segmented mean-pool (batch is sorted) ----------------
__global__ __launch_bounds__(256) void k_pool(const float* __restrict__ h,
                                              const int* __restrict__ batch,
                                              float* __restrict__ pool, float* __restrict__ cnt) {
    int lane = threadIdx.x & 63;
    int wid = (blockIdx.x * 256 + threadIdx.x) >> 6;
    int base = wid * 64;
    if (base >= NN) return;
    int nl = base + lane;
    int bi = (nl < NN) ? batch[nl] : -1;
    int lim = min(64, NN - base);
    float acc = 0.0f;
    int curg = __shfl(bi, 0);
    int runlen = 0;
    for (int i = 0; i < lim; i++) {
        int g = __shfl(bi, i);
        if (g != curg) {  // wave-uniform branch
            atomicAdd(&pool[curg * 64 + lane], acc);
            if (lane == 0) atomicAdd(&cnt[curg], (float)runlen);
            acc = 0.0f; runlen = 0; curg = g;
        }
        acc += h[(size_t)(base + i) * 64 + lane];
        runlen++;
    }
    atomicAdd(&pool[curg * 64 + lane], acc);
    if (lane == 0) atomicAdd(&cnt[curg], (float)runlen);
}

// ---------------- classifier: out[g][c] = (pool[g]/cnt[g]) . Wc[:,c] + bc ----------------
__global__ __launch_bounds__(64) void k_classify(const float* __restrict__ pool,
                                                 const float* __restrict__ cnt,
                                                 const float* __restrict__ Wc,
                                                 const float* __restrict__ bc,
                                                 float* __restrict__ out) {
    int g = blockIdx.x;
    int lane = threadIdx.x;
    float inv = 1.0f / fmaxf(cnt[g], 1.0f);
    float p = pool[g * 64 + lane] * inv;
    float s0 = p * Wc[lane * 3 + 0];
    float s1 = p * Wc[lane * 3 + 1];
    float s2 = p * Wc[lane * 3 + 2];
    for (int o = 32; o > 0; o >>= 1) {
        s0 += __shfl_xor(s0, o);
        s1 += __shfl_xor(s1, o);
        s2 += __shfl_xor(s2, o);
    }
    if (lane == 0) {
        out[g * 3 + 0] = s0 + bc[0];
        out[g * 3 + 1] = s1 + bc[1];
        out[g * 3 + 2] = s2 + bc[2];
    }
}

extern "C" void kernel_launch(void* const* d_in, const int* in_sizes, int n_in,
                              void* d_out, int out_size, void* d_ws, size_t ws_size,
                              hipStream_t stream) {
    const float* x   = (const float*)d_in[0];
    const float* W1  = (const float*)d_in[1];
    const float* b1  = (const float*)d_in[2];
    const float* g1  = (const float*)d_in[3];
    const float* bt1 = (const float*)d_in[4];
    const float* rm1 = (const float*)d_in[5];
    const float* rv1 = (const float*)d_in[6];
    const float* W2  = (const float*)d_in[7];
    const float* b2  = (const float*)d_in[8];
    const float* g2  = (const float*)d_in[9];
    const float* bt2 = (const float*)d_in[10];
    const float* rm2 = (const float*)d_in[11];
    const float* rv2 = (const float*)d_in[12];
    const float* Wc  = (const float*)d_in[13];
    const float* bc  = (const float*)d_in[14];
    const int* ei    = (const int*)d_in[15];
    const int* batch = (const int*)d_in[16];
    const int* srcp = ei;
    const int* dstp = ei + NE;

    char* ws = (char*)d_ws;
    float* dinv = (float*)(ws);                               // NN floats (deg -> dinv in place)
    float* bufA = (float*)(ws + 524288);                      // NN*64 floats
    float* bufB = (float*)(ws + 524288 + 25600000);           // NN*64 floats
    float* pool = (float*)(ws + 524288 + 51200000);           // 512*64 floats
    float* cnt  = (float*)(ws + 524288 + 51200000 + 131072);  // 512 floats

    // degrees -> dinv
    k_init_deg<<<(NN + 255) / 256, 256, 0, stream>>>(dinv);
    k_degree<<<2048, 256, 0, stream>>>(dstp, dinv);
    k_rsqrt<<<(NN + 255) / 256, 256, 0, stream>>>(dinv);

    // layer 1: h1 = x@W1 ; agg = A_hat(h1) ; relu(bn(agg + b1))
    k_gemm<128><<<(NN + 127) / 128, 256, 0, stream>>>(x, W1, bufA, NN);
    hipMemsetAsync(bufB, 0, (size_t)NN * 64 * 4, stream);
    k_aggregate<<<AGG_BLOCKS, 256, 0, stream>>>(bufA, srcp, dstp, dinv, bufB);
    k_post<<<(NN * 64 + 255) / 256, 256, 0, stream>>>(bufB, bufA, dinv, b1, g1, bt1, rm1, rv1);

    // layer 2
    k_gemm<64><<<(NN + 127) / 128, 256, 0, stream>>>(bufB, W2, bufA, NN);
    hipMemsetAsync(bufB, 0, (size_t)NN * 64 * 4, stream);
    k_aggregate<<<AGG_BLOCKS, 256, 0, stream>>>(bufA, srcp, dstp, dinv, bufB);
    k_post<<<(NN * 64 + 255) / 256, 256, 0, stream>>>(bufB, bufA, dinv, b2, g2, bt2, rm2, rv2);

    // mean-pool + classify
    hipMemsetAsync(pool, 0, 512 * 64 * 4 + 512 * 4, stream);
    k_pool<<<(((NN + 63) / 64) + 3) / 4, 256, 0, stream>>>(bufB, batch, pool, cnt);
    k_classify<<<NG, 64, 0, stream>>>(pool, cnt, Wc, bc, (float*)d_out);
}

// Round 2
// 788.125 us; speedup vs baseline: 2.1777x; 2.1777x over previous
//
#include <hip/hip_runtime.h>

#define NN 100000
#define NE 3200000
#define NF 128
#define NH 64
#define NG 512
#define NC 3
#define BN_EPS 1e-5f

// ================= CSR build =================
__global__ __launch_bounds__(256) void k_hist(const int* __restrict__ dst, int* __restrict__ cnt) {
    int stride = gridDim.x * 256;
    for (int e = blockIdx.x * 256 + threadIdx.x; e < NE; e += stride)
        atomicAdd(&cnt[dst[e]], 1);
}

// per-block (1024 elems) exclusive scan; block sums out
__global__ __launch_bounds__(256) void k_scan1(const int* __restrict__ cnt, int* __restrict__ offs,
                                               int* __restrict__ bsum) {
    __shared__ int sh[256];
    int t = threadIdx.x;
    int base = blockIdx.x * 1024 + t * 4;
    int v[4];
#pragma unroll
    for (int j = 0; j < 4; j++) v[j] = (base + j < NN) ? cnt[base + j] : 0;
    int s = v[0] + v[1] + v[2] + v[3];
    sh[t] = s;
    __syncthreads();
    for (int off = 1; off < 256; off <<= 1) {
        int x = (t >= off) ? sh[t - off] : 0;
        __syncthreads();
        sh[t] += x;
        __syncthreads();
    }
    if (t == 255) bsum[blockIdx.x] = sh[255];
    int run = sh[t] - s;  // exclusive prefix of this thread's 4
#pragma unroll
    for (int j = 0; j < 4; j++) {
        if (base + j < NN) offs[base + j] = run;
        run += v[j];
    }
}

__global__ __launch_bounds__(128) void k_scan2(const int* __restrict__ bsum, int* __restrict__ bscan, int nb) {
    __shared__ int sh[128];
    int t = threadIdx.x;
    int v = (t < nb) ? bsum[t] : 0;
    sh[t] = v;
    __syncthreads();
    for (int off = 1; off < 128; off <<= 1) {
        int x = (t >= off) ? sh[t - off] : 0;
        __syncthreads();
        sh[t] += x;
        __syncthreads();
    }
    if (t < nb) bscan[t] = sh[t] - v;
}

// add block offsets; init cursor; compute dinv; write offs[NN]
__global__ __launch_bounds__(256) void k_scan3(const int* __restrict__ cnt, int* __restrict__ offs,
                                               const int* __restrict__ bscan, int* __restrict__ cursor,
                                               float* __restrict__ dinv) {
    int i = blockIdx.x * 256 + threadIdx.x;
    if (i >= NN) return;
    int o = offs[i] + bscan[i >> 10];
    offs[i] = o;
    cursor[i] = o;
    dinv[i] = rsqrtf((float)(cnt[i] + 1));  // +1 self-loop
    if (i == 0) offs[NN] = NE;
}

// scatter edges into CSR order; record = (src, norm-bits)
__global__ __launch_bounds__(256) void k_fill(const int* __restrict__ src, const int* __restrict__ dst,
                                              const float* __restrict__ dinv, int* __restrict__ cursor,
                                              int2* __restrict__ es) {
    int stride = gridDim.x * 256;
    for (int e = blockIdx.x * 256 + threadIdx.x; e < NE; e += stride) {
        int s = src[e], d = dst[e];
        int pos = atomicAdd(&cursor[d], 1);
        float nrm = dinv[s] * dinv[d];
        es[pos] = make_int2(s, __float_as_int(nrm));
    }
}

// ================= GEMM: out[M][64] = X[M][K] @ W[K][64] =================
template <int K>
__global__ __launch_bounds__(256) void k_gemm(const float* __restrict__ X,
                                              const float* __restrict__ W,
                                              float* __restrict__ out, int M) {
    __shared__ float xs[128 * 68];
    __shared__ float ws[64 * 64];
    const int t = threadIdx.x;
    const int row0 = blockIdx.x * 128;
    const int rg = t >> 3;
    const int f0 = (t & 7) * 8;

    float acc[4][8];
#pragma unroll
    for (int j = 0; j < 4; j++)
#pragma unroll
        for (int c = 0; c < 8; c++) acc[j][c] = 0.0f;

    for (int kc = 0; kc < K; kc += 64) {
        __syncthreads();
        const float4* Wg = (const float4*)(W + (size_t)kc * 64);
        float4* ws4 = (float4*)ws;
#pragma unroll
        for (int i = 0; i < 4; i++) ws4[t + i * 256] = Wg[t + i * 256];
#pragma unroll
        for (int p = 0; p < 8; p++) {
            int rr = p * 16 + (t >> 4);
            int c4 = (t & 15) * 4;
            int row = row0 + rr;
            float4 v = make_float4(0.f, 0.f, 0.f, 0.f);
            if (row < M) v = *(const float4*)(X + (size_t)row * K + kc + c4);
            *(float4*)(&xs[rr * 68 + c4]) = v;
        }
        __syncthreads();

        for (int kk = 0; kk < 64; kk += 4) {
            float4 xv[4];
#pragma unroll
            for (int j = 0; j < 4; j++)
                xv[j] = *(const float4*)(&xs[(rg + 32 * j) * 68 + kk]);
#pragma unroll
            for (int kki = 0; kki < 4; kki++) {
                float4 w0 = *(const float4*)(&ws[(kk + kki) * 64 + f0]);
                float4 w1 = *(const float4*)(&ws[(kk + kki) * 64 + f0 + 4]);
#pragma unroll
                for (int j = 0; j < 4; j++) {
                    float a = (&xv[j].x)[kki];
                    acc[j][0] = fmaf(a, w0.x, acc[j][0]);
                    acc[j][1] = fmaf(a, w0.y, acc[j][1]);
                    acc[j][2] = fmaf(a, w0.z, acc[j][2]);
                    acc[j][3] = fmaf(a, w0.w, acc[j][3]);
                    acc[j][4] = fmaf(a, w1.x, acc[j][4]);
                    acc[j][5] = fmaf(a, w1.y, acc[j][5]);
                    acc[j][6] = fmaf(a, w1.z, acc[j][6]);
                    acc[j][7] = fmaf(a, w1.w, acc[j][7]);
                }
            }
        }
    }

#pragma unroll
    for (int j = 0; j < 4; j++) {
        int row = row0 + rg + 32 * j;
        if (row < M) {
            float4* o = (float4*)(out + (size_t)row * 64 + f0);
            o[0] = make_float4(acc[j][0], acc[j][1], acc[j][2], acc[j][3]);
            o[1] = make_float4(acc[j][4], acc[j][5], acc[j][6], acc[j][7]);
        }
    }
}

// ============ CSR aggregation, wave per node, fused epilogue ============
// acc[lane] = sum_{e in CSR[node]} h[src_e][lane]*norm_e + h[node][lane]*dinv[node]^2
// then bias + BN(eval) + ReLU, single write.
__global__ __launch_bounds__(256) void k_agg2(const float* __restrict__ h,
                                              const int2* __restrict__ es,
                                              const int* __restrict__ offs,
                                              const float* __restrict__ dinv,
                                              const float* __restrict__ bias,
                                              const float* __restrict__ gam,
                                              const float* __restrict__ bet,
                                              const float* __restrict__ rm,
                                              const float* __restrict__ rv,
                                              float* __restrict__ out) {
    const int lane = threadIdx.x & 63;
    const int node = (blockIdx.x * 256 + threadIdx.x) >> 6;
    if (node >= NN) return;
    const int beg = offs[node];
    const int end = offs[node + 1];
    const float di = dinv[node];
    float acc = h[(size_t)node * 64 + lane] * di * di;

    for (int c = beg; c < end; c += 64) {
        int m = end - c;
        if (m > 64) m = 64;
        int2 rec = (lane < m) ? es[c + lane] : make_int2(0, 0);  // zero norm pads
        int jm = (m + 3) & ~3;
        for (int j = 0; j < jm; j += 4) {
#pragma unroll
            for (int u = 0; u < 4; u++) {
                int s = __shfl(rec.x, j + u);
                float nrm = __int_as_float(__shfl(rec.y, j + u));
                acc = fmaf(h[(size_t)s * 64 + lane], nrm, acc);
            }
        }
    }

    float val = acc + bias[lane];
    float y = (val - rm[lane]) * rsqrtf(rv[lane] + BN_EPS) * gam[lane] + bet[lane];
    out[(size_t)node * 64 + lane] = fmaxf(y, 0.0f);
}

// ================= segmented mean-pool (batch sorted) =================
__global__ __launch_bounds__(256) void k_pool(const float* __restrict__ h,
                                              const int* __restrict__ batch,
                                              float* __restrict__ pool, float* __restrict__ cnt) {
    int lane = threadIdx.x & 63;
    int wid = (blockIdx.x * 256 + threadIdx.x) >> 6;
    int base = wid * 64;
    if (base >= NN) return;
    int nl = base + lane;
    int bi = (nl < NN) ? batch[nl] : -1;
    int lim = min(64, NN - base);
    float acc = 0.0f;
    int curg = __shfl(bi, 0);
    int runlen = 0;
    for (int i = 0; i < lim; i++) {
        int g = __shfl(bi, i);
        if (g != curg) {
            atomicAdd(&pool[curg * 64 + lane], acc);
            if (lane == 0) atomicAdd(&cnt[curg], (float)runlen);
            acc = 0.0f; runlen = 0; curg = g;
        }
        acc += h[(size_t)(base + i) * 64 + lane];
        runlen++;
    }
    atomicAdd(&pool[curg * 64 + lane], acc);
    if (lane == 0) atomicAdd(&cnt[curg], (float)runlen);
}

__global__ __launch_bounds__(64) void k_classify(const float* __restrict__ pool,
                                                 const float* __restrict__ cnt,
                                                 const float* __restrict__ Wc,
                                                 const float* __restrict__ bc,
                                                 float* __restrict__ out) {
    int g = blockIdx.x;
    int lane = threadIdx.x;
    float inv = 1.0f / fmaxf(cnt[g], 1.0f);
    float p = pool[g * 64 + lane] * inv;
    float s0 = p * Wc[lane * 3 + 0];
    float s1 = p * Wc[lane * 3 + 1];
    float s2 = p * Wc[lane * 3 + 2];
    for (int o = 32; o > 0; o >>= 1) {
        s0 += __shfl_xor(s0, o);
        s1 += __shfl_xor(s1, o);
        s2 += __shfl_xor(s2, o);
    }
    if (lane == 0) {
        out[g * 3 + 0] = s0 + bc[0];
        out[g * 3 + 1] = s1 + bc[1];
        out[g * 3 + 2] = s2 + bc[2];
    }
}

extern "C" void kernel_launch(void* const* d_in, const int* in_sizes, int n_in,
                              void* d_out, int out_size, void* d_ws, size_t ws_size,
                              hipStream_t stream) {
    const float* x   = (const float*)d_in[0];
    const float* W1  = (const float*)d_in[1];
    const float* b1  = (const float*)d_in[2];
    const float* g1  = (const float*)d_in[3];
    const float* bt1 = (const float*)d_in[4];
    const float* rm1 = (const float*)d_in[5];
    const float* rv1 = (const float*)d_in[6];
    const float* W2  = (const float*)d_in[7];
    const float* b2  = (const float*)d_in[8];
    const float* g2  = (const float*)d_in[9];
    const float* bt2 = (const float*)d_in[10];
    const float* rm2 = (const float*)d_in[11];
    const float* rv2 = (const float*)d_in[12];
    const float* Wc  = (const float*)d_in[13];
    const float* bc  = (const float*)d_in[14];
    const int* ei    = (const int*)d_in[15];
    const int* batch = (const int*)d_in[16];
    const int* srcp = ei;
    const int* dstp = ei + NE;

    char* ws = (char*)d_ws;
    int*   cnt    = (int*)(ws);                       // NN
    int*   offs   = (int*)(ws + 400000);              // NN+1
    int*   cursor = (int*)(ws + 800064);              // NN
    int*   bsum   = (int*)(ws + 1200064);             // 128
    int*   bscan  = (int*)(ws + 1200576);             // 128
    float* dinv   = (float*)(ws + 1201088);           // NN
    int2*  es     = (int2*)(ws + 1601088);            // NE int2 = 25.6 MB
    float* bufA   = (float*)(ws + 27201088);          // NN*64
    float* bufB   = (float*)(ws + 52801088);          // NN*64
    float* pool   = (float*)(ws + 78401088);          // 512*64
    float* gcnt   = (float*)(ws + 78532160);          // 512

    // ---- CSR build (shared by both layers) ----
    hipMemsetAsync(cnt, 0, (size_t)NN * 4, stream);
    k_hist<<<2048, 256, 0, stream>>>(dstp, cnt);
    int nb = (NN + 1023) / 1024;  // 98
    k_scan1<<<nb, 256, 0, stream>>>(cnt, offs, bsum);
    k_scan2<<<1, 128, 0, stream>>>(bsum, bscan, nb);
    k_scan3<<<(NN + 255) / 256, 256, 0, stream>>>(cnt, offs, bscan, cursor, dinv);
    k_fill<<<2048, 256, 0, stream>>>(srcp, dstp, dinv, cursor, es);

    // ---- layer 1 ----
    k_gemm<128><<<(NN + 127) / 128, 256, 0, stream>>>(x, W1, bufA, NN);
    k_agg2<<<(NN * 64 + 255) / 256, 256, 0, stream>>>(bufA, es, offs, dinv, b1, g1, bt1, rm1, rv1, bufB);

    // ---- layer 2 ----
    k_gemm<64><<<(NN + 127) / 128, 256, 0, stream>>>(bufB, W2, bufA, NN);
    k_agg2<<<(NN * 64 + 255) / 256, 256, 0, stream>>>(bufA, es, offs, dinv, b2, g2, bt2, rm2, rv2, bufB);

    // ---- pool + classify ----
    hipMemsetAsync(pool, 0, 512 * 64 * 4 + 512 * 4, stream);
    k_pool<<<(((NN + 63) / 64) + 3) / 4, 256, 0, stream>>>(bufB, batch, pool, gcnt);
    k_classify<<<NG, 64, 0, stream>>>(pool, gcnt, Wc, bc, (float*)d_out);
}